// Round 4
// baseline (2336.541 us; speedup 1.0000x reference)
//
#include <hip/hip_runtime.h>

// n must be <= 256*1024 for the bucket scheme (bucket = dst >> 10, B <= 256).

// ---------------- CSR build: tp (small, 200K edges) — old path ----------------

__global__ __launch_bounds__(256) void hist_tp_kernel(
    const int* __restrict__ ei_tp, int E_tp, int* __restrict__ deg_tp)
{
    int i = blockIdx.x * 256 + threadIdx.x;
    if (i < E_tp) atomicAdd(&deg_tp[ei_tp[E_tp + i]], 1);
}

__global__ __launch_bounds__(256) void alloc_tp_kernel(
    int n, const int* __restrict__ deg_tp,
    int* __restrict__ row_tp, int* __restrict__ next_tp, int* __restrict__ ctr)
{
    int i = blockIdx.x * 256 + threadIdx.x;
    if (i >= n) return;
    int d = deg_tp[i];
    int r = atomicAdd(&ctr[0], d);
    row_tp[i] = r; next_tp[i] = r;
}

__global__ __launch_bounds__(256) void fill_tp_kernel(
    const int* __restrict__ ei_tp, int E_tp,
    int* __restrict__ next_tp, int* __restrict__ col_tp)
{
    int i = blockIdx.x * 256 + threadIdx.x;
    if (i >= E_tp) return;
    int src = ei_tp[i];
    int dst = ei_tp[E_tp + i];
    col_tp[atomicAdd(&next_tp[dst], 1)] = src;
}

// ---------------- CSR build: it (3.2M edges) — two-level multisplit ----------------

__global__ __launch_bounds__(256) void bucket_count_kernel(
    const int* __restrict__ ei_it, int E_it, int B, int* __restrict__ bcnt)
{
    __shared__ int h[256];
    h[threadIdx.x] = 0;
    __syncthreads();
    const int stride = gridDim.x * 256;
    for (int i = blockIdx.x * 256 + threadIdx.x; i < E_it; i += stride)
        atomicAdd(&h[ei_it[E_it + i] >> 10], 1);
    __syncthreads();
    int v = h[threadIdx.x];
    if (threadIdx.x < B && v) atomicAdd(&bcnt[threadIdx.x], v);
}

__global__ __launch_bounds__(256) void bucket_prefix_kernel(
    int B, const int* __restrict__ bcnt, int* __restrict__ bbase, int* __restrict__ bcursor)
{
    __shared__ int s[256];
    const int t = threadIdx.x;
    s[t] = (t < B) ? bcnt[t] : 0;
    __syncthreads();
    for (int off = 1; off < 256; off <<= 1) {
        int v = (t >= off) ? s[t - off] : 0;
        __syncthreads();
        if (t >= off) s[t] += v;
        __syncthreads();
    }
    if (t == 0) bbase[0] = 0;
    if (t < B) {
        bbase[t + 1] = s[t];
        bcursor[t] = s[t] - bcnt[t];
    }
}

__global__ __launch_bounds__(256) void multisplit_kernel(
    const int* __restrict__ ei_it, int E_it,
    int* __restrict__ bcursor, unsigned long long* __restrict__ ebuf)
{
    __shared__ int cnt[256];
    __shared__ int gbase[256];
    const int tid  = threadIdx.x;
    const int base = blockIdx.x * 2048;
    cnt[tid] = 0;
    __syncthreads();

    int src[8], dst[8], rk[8], bk[8];
#pragma unroll
    for (int k = 0; k < 8; k++) {
        int i = base + k * 256 + tid;
        if (i < E_it) {
            src[k] = ei_it[i];
            dst[k] = ei_it[E_it + i];
            bk[k]  = dst[k] >> 10;
            rk[k]  = atomicAdd(&cnt[bk[k]], 1);
        } else rk[k] = -1;
    }
    __syncthreads();
    int c = cnt[tid];
    if (c) gbase[tid] = atomicAdd(&bcursor[tid], c);
    __syncthreads();
#pragma unroll
    for (int k = 0; k < 8; k++) {
        if (rk[k] >= 0) {
            int pos = gbase[bk[k]] + rk[k];
            ebuf[pos] = ((unsigned long long)(unsigned)dst[k] << 32) | (unsigned)src[k];
        }
    }
}

__global__ __launch_bounds__(256) void csr_it_kernel(
    int n, const unsigned long long* __restrict__ ebuf, const int* __restrict__ bbase,
    int* __restrict__ row_it, int* __restrict__ deg_it,
    float* __restrict__ inv_cnt, int* __restrict__ col_it)
{
    __shared__ int ldeg[1024];
    __shared__ int lnext[1024];
    __shared__ int lpart[256];
    const int b = blockIdx.x;
    const int t = threadIdx.x;
    const int node_lo = b << 10;
    const int nn = min(1024, n - node_lo);
    const int e0 = bbase[b], e1 = bbase[b + 1];

    for (int i = t; i < nn; i += 256) ldeg[i] = 0;
    __syncthreads();
    for (int i = e0 + t; i < e1; i += 256)
        atomicAdd(&ldeg[(int)(ebuf[i] >> 32) - node_lo], 1);
    __syncthreads();

    const int i4 = 4 * t;
    int l0 = (i4     < nn) ? ldeg[i4]     : 0;
    int l1 = (i4 + 1 < nn) ? ldeg[i4 + 1] : 0;
    int l2 = (i4 + 2 < nn) ? ldeg[i4 + 2] : 0;
    int l3 = (i4 + 3 < nn) ? ldeg[i4 + 3] : 0;
    const int lsum = l0 + l1 + l2 + l3;
    lpart[t] = lsum;
    __syncthreads();
    for (int off = 1; off < 256; off <<= 1) {
        int v = (t >= off) ? lpart[t - off] : 0;
        __syncthreads();
        if (t >= off) lpart[t] += v;
        __syncthreads();
    }
    const int ex = lpart[t] - lsum;

    const int p[4] = {ex, ex + l0, ex + l0 + l1, ex + l0 + l1 + l2};
    const int l[4] = {l0, l1, l2, l3};
#pragma unroll
    for (int k = 0; k < 4; k++) {
        int i = i4 + k;
        if (i < nn) {
            lnext[i] = p[k];
            row_it[node_lo + i]  = e0 + p[k];
            deg_it[node_lo + i]  = l[k];
            inv_cnt[node_lo + i] = 1.0f / (float)max(l[k], 1);
        }
    }
    __syncthreads();
    for (int i = e0 + t; i < e1; i += 256) {
        unsigned long long v = ebuf[i];
        int dstl = (int)(v >> 32) - node_lo;
        int pos  = atomicAdd(&lnext[dstl], 1);
        col_it[e0 + pos] = (int)(v & 0xffffffffu);
    }
}

// ---------------- Aggregation (C=32): one wave per node ----------------
// __launch_bounds__(256,8): pin VGPR<=64 so 32 waves/CU hide gather latency.

__global__ __launch_bounds__(256, 8) void agg32_kernel(
    int n, const float* __restrict__ hin,
    const int* __restrict__ row_it, const int* __restrict__ deg_it, const int* __restrict__ col_it,
    const int* __restrict__ row_tp, const int* __restrict__ deg_tp, const int* __restrict__ col_tp,
    const float* __restrict__ inv_cnt, float* __restrict__ agg)
{
    const int wave = threadIdx.x >> 6;
    const int lane = threadIdx.x & 63;
    const int g = lane >> 3;
    const int q = lane & 7;
    const int node = blockIdx.x * 4 + wave;
    if (node >= n) return;

    float4 aA = make_float4(0.f, 0.f, 0.f, 0.f);
    float4 aM = make_float4(0.f, 0.f, 0.f, 0.f);

    {
        const int rs = row_tp[node], d = deg_tp[node];
        for (int e = g; e < d; e += 8) {
            const int j = col_tp[rs + e];
            const float4 v = *(const float4*)&hin[(size_t)j * 32 + q * 4];
            aA.x += v.x; aA.y += v.y; aA.z += v.z; aA.w += v.w;
        }
    }
    {
        const int rs = row_it[node], d = deg_it[node];
        int e = g;
        for (; e + 8 < d; e += 16) {
            const int j0 = col_it[rs + e];
            const int j1 = col_it[rs + e + 8];
            const float4 v0 = *(const float4*)&hin[(size_t)j0 * 32 + q * 4];
            const float4 v1 = *(const float4*)&hin[(size_t)j1 * 32 + q * 4];
            aM.x += v0.x + v1.x; aM.y += v0.y + v1.y;
            aM.z += v0.z + v1.z; aM.w += v0.w + v1.w;
        }
        for (; e < d; e += 8) {
            const int j = col_it[rs + e];
            const float4 v = *(const float4*)&hin[(size_t)j * 32 + q * 4];
            aM.x += v.x; aM.y += v.y; aM.z += v.z; aM.w += v.w;
        }
    }

#pragma unroll
    for (int mask = 8; mask < 64; mask <<= 1) {
        aA.x += __shfl_xor(aA.x, mask); aA.y += __shfl_xor(aA.y, mask);
        aA.z += __shfl_xor(aA.z, mask); aA.w += __shfl_xor(aA.w, mask);
        aM.x += __shfl_xor(aM.x, mask); aM.y += __shfl_xor(aM.y, mask);
        aM.z += __shfl_xor(aM.z, mask); aM.w += __shfl_xor(aM.w, mask);
    }

    if (lane < 8) {
        const float ic = inv_cnt[node];
        aM.x *= ic; aM.y *= ic; aM.z *= ic; aM.w *= ic;
        *(float4*)&agg[(size_t)node * 64 + q * 4]      = aA;
        *(float4*)&agg[(size_t)node * 64 + 32 + q * 4] = aM;
    }
}

// ---------------- Aggregation (C=6, head) ----------------

__global__ __launch_bounds__(256, 8) void agg6_kernel(
    int n, const float* __restrict__ hin,
    const int* __restrict__ row_it, const int* __restrict__ deg_it, const int* __restrict__ col_it,
    const int* __restrict__ row_tp, const int* __restrict__ deg_tp, const int* __restrict__ col_tp,
    const float* __restrict__ inv_cnt, float* __restrict__ agg)
{
    const int wave = threadIdx.x >> 6;
    const int lane = threadIdx.x & 63;
    const int g = lane >> 3;
    const int c = lane & 7;
    const int cc = (c < 6) ? c : 0;
    const int node = blockIdx.x * 4 + wave;
    if (node >= n) return;

    float aA = 0.f, aM = 0.f;
    {
        const int rs = row_tp[node], d = deg_tp[node];
        for (int e = g; e < d; e += 8) {
            const int j = col_tp[rs + e];
            aA += hin[(size_t)j * 6 + cc];
        }
    }
    {
        const int rs = row_it[node], d = deg_it[node];
        int e = g;
        for (; e + 8 < d; e += 16) {
            const int j0 = col_it[rs + e];
            const int j1 = col_it[rs + e + 8];
            aM += hin[(size_t)j0 * 6 + cc] + hin[(size_t)j1 * 6 + cc];
        }
        for (; e < d; e += 8) {
            const int j = col_it[rs + e];
            aM += hin[(size_t)j * 6 + cc];
        }
    }

#pragma unroll
    for (int mask = 8; mask < 64; mask <<= 1) {
        aA += __shfl_xor(aA, mask);
        aM += __shfl_xor(aM, mask);
    }

    if (lane < 6) {
        agg[(size_t)node * 12 + c]     = aA;
        agg[(size_t)node * 12 + 6 + c] = aM * inv_cnt[node];
    }
}

// ---------------- Per-layer GEMM ----------------

template <int CI, bool RESID>
__global__ __launch_bounds__(128) void gemm_kernel(
    int n, const float* __restrict__ agg, const float* __restrict__ hin,
    const float* __restrict__ Wrel0, const float* __restrict__ Wrel1,
    const float* __restrict__ Wroot0, const float* __restrict__ Wroot1,
    const float* __restrict__ bias0, const float* __restrict__ bias1,
    float* __restrict__ hout)
{
    constexpr int K  = 3 * CI;
    constexpr int KC = (CI == 6) ? 18 : 16;
    constexpr int NCHUNK = K / KC;
    constexpr int LDA = 260;

    __shared__ float sW[K * 32];
    __shared__ float sB[32];
    __shared__ float sA[KC * LDA];

    const int tid = threadIdx.x;
    for (int idx = tid; idx < K * 32; idx += 128) {
        int k = idx >> 5, co = idx & 31;
        float w;
        if (k < CI)            w = Wrel0[k * 32 + co];
        else if (k < 2 * CI)   w = Wrel1[(k - CI) * 32 + co];
        else                   w = Wroot0[(k - 2 * CI) * 32 + co] + Wroot1[(k - 2 * CI) * 32 + co];
        sW[idx] = w;
    }
    if (tid < 32) sB[tid] = bias0[tid] + bias1[tid];

    const int n0 = blockIdx.x * 256;
    const int cg = tid & 3;
    const int ng = tid >> 2;

    float acc[8][8];
#pragma unroll
    for (int i = 0; i < 8; i++)
#pragma unroll
        for (int j = 0; j < 8; j++) acc[i][j] = 0.f;

    for (int ch = 0; ch < NCHUNK; ch++) {
        const int k0 = ch * KC;
        __syncthreads();
        for (int idx = tid; idx < KC * 256; idx += 128) {
            int kk, nn;
            if constexpr ((KC & (KC - 1)) == 0) { kk = idx & (KC - 1); nn = idx >> 4; }
            else                                { kk = idx % KC;       nn = idx / KC; }
            int node = n0 + nn;
            int k = k0 + kk;
            float v = 0.f;
            if (node < n) {
                v = (k < 2 * CI) ? agg[(size_t)node * (2 * CI) + k]
                                 : hin[(size_t)node * CI + (k - 2 * CI)];
            }
            sA[kk * LDA + nn] = v;
        }
        __syncthreads();
#pragma unroll
        for (int kk = 0; kk < KC; kk++) {
            const float4 a0 = *(const float4*)&sA[kk * LDA + ng * 8];
            const float4 a1 = *(const float4*)&sA[kk * LDA + ng * 8 + 4];
            const int k = k0 + kk;
            const float4 w0 = *(const float4*)&sW[k * 32 + cg * 8];
            const float4 w1 = *(const float4*)&sW[k * 32 + cg * 8 + 4];
            const float av[8] = {a0.x, a0.y, a0.z, a0.w, a1.x, a1.y, a1.z, a1.w};
            const float wv[8] = {w0.x, w0.y, w0.z, w0.w, w1.x, w1.y, w1.z, w1.w};
#pragma unroll
            for (int i = 0; i < 8; i++)
#pragma unroll
                for (int j = 0; j < 8; j++) acc[i][j] += av[i] * wv[j];
        }
    }

    const int cbase = cg * 8;
#pragma unroll
    for (int i = 0; i < 8; i++) {
        int node = n0 + ng * 8 + i;
        if (node < n) {
            float r[8];
#pragma unroll
            for (int j = 0; j < 8; j++) r[j] = acc[i][j] + sB[cbase + j];
            if (RESID) {
                const float4 h0 = *(const float4*)&hin[(size_t)node * 32 + cbase];
                const float4 h1 = *(const float4*)&hin[(size_t)node * 32 + cbase + 4];
                r[0] += h0.x; r[1] += h0.y; r[2] += h0.z; r[3] += h0.w;
                r[4] += h1.x; r[5] += h1.y; r[6] += h1.z; r[7] += h1.w;
            }
#pragma unroll
            for (int j = 0; j < 8; j++) r[j] = fmaxf(r[j], 0.f);
            *(float4*)&hout[(size_t)node * 32 + cbase]     = make_float4(r[0], r[1], r[2], r[3]);
            *(float4*)&hout[(size_t)node * 32 + cbase + 4] = make_float4(r[4], r[5], r[6], r[7]);
        }
    }
}

// ---------------- Final linear: out = h @ Wout + bout ----------------
// v2: 64-node x 128-col tile, per-thread 4x8 (acc=32 VGPR) to fix the
// VGPR=256 / 10% occupancy cliff seen in R3 profiling.

__global__ __launch_bounds__(256, 4) void final_kernel(
    int n, const float* __restrict__ h, const float* __restrict__ Wout,
    const float* __restrict__ bout, float* __restrict__ out)
{
    constexpr int LDH = 68;   // 64+4: 16B-aligned rows, breaks pow2 stride
    __shared__ float sW[32 * 128];
    __shared__ float sB[128];
    __shared__ float sHT[32 * LDH];

    const int tid = threadIdx.x;
    for (int idx = tid; idx < 4096; idx += 256) sW[idx] = Wout[idx];
    if (tid < 128) sB[tid] = bout[tid];

    const int n0 = blockIdx.x * 64;
    for (int idx = tid; idx < 2048; idx += 256) {
        int k = idx & 31, nn = idx >> 5;
        int node = n0 + nn;
        sHT[k * LDH + nn] = (node < n) ? h[(size_t)node * 32 + k] : 0.f;
    }
    __syncthreads();

    const int cg = tid & 15;   // 16 col groups x 8 cols
    const int ng = tid >> 4;   // 16 node groups x 4 nodes
    float acc[4][8];
#pragma unroll
    for (int i = 0; i < 4; i++)
#pragma unroll
        for (int j = 0; j < 8; j++) acc[i][j] = 0.f;

#pragma unroll
    for (int k = 0; k < 32; k++) {
        const float4 a  = *(const float4*)&sHT[k * LDH + ng * 4];
        const float4 w0 = *(const float4*)&sW[k * 128 + cg * 8];
        const float4 w1 = *(const float4*)&sW[k * 128 + cg * 8 + 4];
        const float av[4] = {a.x, a.y, a.z, a.w};
        const float wv[8] = {w0.x, w0.y, w0.z, w0.w, w1.x, w1.y, w1.z, w1.w};
#pragma unroll
        for (int i = 0; i < 4; i++)
#pragma unroll
            for (int j = 0; j < 8; j++) acc[i][j] += av[i] * wv[j];
    }

    const int cbase = cg * 8;
#pragma unroll
    for (int i = 0; i < 4; i++) {
        int node = n0 + ng * 4 + i;
        if (node < n) {
            float r[8];
#pragma unroll
            for (int j = 0; j < 8; j++) r[j] = acc[i][j] + sB[cbase + j];
            *(float4*)&out[(size_t)node * 128 + cbase]     = make_float4(r[0], r[1], r[2], r[3]);
            *(float4*)&out[(size_t)node * 128 + cbase + 4] = make_float4(r[4], r[5], r[6], r[7]);
        }
    }
}

// ---------------- launch ----------------

extern "C" void kernel_launch(void* const* d_in, const int* in_sizes, int n_in,
                              void* d_out, int out_size, void* d_ws, size_t ws_size,
                              hipStream_t stream)
{
    const float* x      = (const float*)d_in[0];
    const int*   ei_tp  = (const int*)d_in[1];
    const int*   ei_it  = (const int*)d_in[2];
    const float* W0_rel  = (const float*)d_in[3];
    const float* W0_root = (const float*)d_in[4];
    const float* b0      = (const float*)d_in[5];
    const float* W_rel   = (const float*)d_in[6];
    const float* W_root  = (const float*)d_in[7];
    const float* b       = (const float*)d_in[8];
    const float* Wout    = (const float*)d_in[9];
    const float* bout    = (const float*)d_in[10];
    float* out = (float*)d_out;

    const int n    = in_sizes[0] / 6;
    const int E_tp = in_sizes[1] / 2;
    const int E_it = in_sizes[2] / 2;
    const int B    = (n + 1023) >> 10;

    float* h0      = (float*)d_ws;
    float* h1      = h0 + (size_t)n * 32;
    int*   deg_it  = (int*)(h1 + (size_t)n * 32);
    int*   row_it  = deg_it + n;
    float* inv_cnt = (float*)(row_it + n);
    int*   deg_tp  = (int*)(inv_cnt + n);
    int*   ctr     = deg_tp + n;
    int*   bcnt    = ctr + 1;
    int*   bbase   = bcnt + 256;
    int*   bcursor = bbase + 257;
    int*   row_tp  = bcursor + 256;
    int*   next_tp = row_tp + n;
    int*   col_it  = next_tp + n;
    int*   col_tp  = col_it + E_it;
    unsigned long long* ebuf = (unsigned long long*)d_out;
    float* aggbuf = (float*)d_out;

    hipMemsetAsync(deg_tp, 0, (size_t)(n + 1 + 256) * sizeof(int), stream);

    bucket_count_kernel<<<512, 256, 0, stream>>>(ei_it, E_it, B, bcnt);
    bucket_prefix_kernel<<<1, 256, 0, stream>>>(B, bcnt, bbase, bcursor);
    multisplit_kernel<<<(E_it + 2047) / 2048, 256, 0, stream>>>(ei_it, E_it, bcursor, ebuf);
    csr_it_kernel<<<B, 256, 0, stream>>>(n, ebuf, bbase, row_it, deg_it, inv_cnt, col_it);

    hist_tp_kernel<<<(E_tp + 255) / 256, 256, 0, stream>>>(ei_tp, E_tp, deg_tp);
    alloc_tp_kernel<<<(n + 255) / 256, 256, 0, stream>>>(n, deg_tp, row_tp, next_tp, ctr);
    fill_tp_kernel<<<(E_tp + 255) / 256, 256, 0, stream>>>(ei_tp, E_tp, next_tp, col_tp);

    const int agg_blocks  = (n + 3) / 4;
    const int gemm_blocks = (n + 255) / 256;

    agg6_kernel<<<agg_blocks, 256, 0, stream>>>(n, x, row_it, deg_it, col_it,
                                                row_tp, deg_tp, col_tp, inv_cnt, aggbuf);
    gemm_kernel<6, false><<<gemm_blocks, 128, 0, stream>>>(
        n, aggbuf, x,
        W0_rel, W0_rel + 192, W0_root, W0_root + 192, b0, b0 + 32, h0);

    float* hin  = h0;
    float* hout = h1;
    for (int l = 0; l < 4; l++) {
        agg32_kernel<<<agg_blocks, 256, 0, stream>>>(n, hin, row_it, deg_it, col_it,
                                                     row_tp, deg_tp, col_tp, inv_cnt, aggbuf);
        gemm_kernel<32, true><<<gemm_blocks, 128, 0, stream>>>(
            n, aggbuf, hin,
            W_rel + (size_t)l * 2048, W_rel + (size_t)l * 2048 + 1024,
            W_root + (size_t)l * 2048, W_root + (size_t)l * 2048 + 1024,
            b + (size_t)l * 64, b + (size_t)l * 64 + 32, hout);
        float* t = hin; hin = hout; hout = t;
    }

    final_kernel<<<(n + 63) / 64, 256, 0, stream>>>(n, hin, Wout, bout, out);
}

// Round 5
// 1254.726 us; speedup vs baseline: 1.8622x; 1.8622x over previous
//
#include <hip/hip_runtime.h>

// n must be <= 256*1024 for the bucket scheme (bucket = dst >> 10, B <= 256).

// ---------------- CSR build: tp (small, 200K edges) — old path ----------------

__global__ __launch_bounds__(256) void hist_tp_kernel(
    const int* __restrict__ ei_tp, int E_tp, int* __restrict__ deg_tp)
{
    int i = blockIdx.x * 256 + threadIdx.x;
    if (i < E_tp) atomicAdd(&deg_tp[ei_tp[E_tp + i]], 1);
}

__global__ __launch_bounds__(256) void alloc_tp_kernel(
    int n, const int* __restrict__ deg_tp,
    int* __restrict__ row_tp, int* __restrict__ next_tp, int* __restrict__ ctr)
{
    int i = blockIdx.x * 256 + threadIdx.x;
    if (i >= n) return;
    int d = deg_tp[i];
    int r = atomicAdd(&ctr[0], d);
    row_tp[i] = r; next_tp[i] = r;
}

__global__ __launch_bounds__(256) void fill_tp_kernel(
    const int* __restrict__ ei_tp, int E_tp,
    int* __restrict__ next_tp, int* __restrict__ col_tp)
{
    int i = blockIdx.x * 256 + threadIdx.x;
    if (i >= E_tp) return;
    int src = ei_tp[i];
    int dst = ei_tp[E_tp + i];
    col_tp[atomicAdd(&next_tp[dst], 1)] = src;
}

// ---------------- CSR build: it (3.2M edges) — two-level multisplit ----------------

__global__ __launch_bounds__(256) void bucket_count_kernel(
    const int* __restrict__ ei_it, int E_it, int B, int* __restrict__ bcnt)
{
    __shared__ int h[256];
    h[threadIdx.x] = 0;
    __syncthreads();
    const int stride = gridDim.x * 256;
    for (int i = blockIdx.x * 256 + threadIdx.x; i < E_it; i += stride)
        atomicAdd(&h[ei_it[E_it + i] >> 10], 1);
    __syncthreads();
    int v = h[threadIdx.x];
    if (threadIdx.x < B && v) atomicAdd(&bcnt[threadIdx.x], v);
}

__global__ __launch_bounds__(256) void bucket_prefix_kernel(
    int B, const int* __restrict__ bcnt, int* __restrict__ bbase, int* __restrict__ bcursor)
{
    __shared__ int s[256];
    const int t = threadIdx.x;
    s[t] = (t < B) ? bcnt[t] : 0;
    __syncthreads();
    for (int off = 1; off < 256; off <<= 1) {
        int v = (t >= off) ? s[t - off] : 0;
        __syncthreads();
        if (t >= off) s[t] += v;
        __syncthreads();
    }
    if (t == 0) bbase[0] = 0;
    if (t < B) {
        bbase[t + 1] = s[t];
        bcursor[t] = s[t] - bcnt[t];
    }
}

__global__ __launch_bounds__(256) void multisplit_kernel(
    const int* __restrict__ ei_it, int E_it,
    int* __restrict__ bcursor, unsigned long long* __restrict__ ebuf)
{
    __shared__ int cnt[256];
    __shared__ int gbase[256];
    const int tid  = threadIdx.x;
    const int base = blockIdx.x * 2048;
    cnt[tid] = 0;
    __syncthreads();

    int src[8], dst[8], rk[8], bk[8];
#pragma unroll
    for (int k = 0; k < 8; k++) {
        int i = base + k * 256 + tid;
        if (i < E_it) {
            src[k] = ei_it[i];
            dst[k] = ei_it[E_it + i];
            bk[k]  = dst[k] >> 10;
            rk[k]  = atomicAdd(&cnt[bk[k]], 1);
        } else rk[k] = -1;
    }
    __syncthreads();
    int c = cnt[tid];
    if (c) gbase[tid] = atomicAdd(&bcursor[tid], c);
    __syncthreads();
#pragma unroll
    for (int k = 0; k < 8; k++) {
        if (rk[k] >= 0) {
            int pos = gbase[bk[k]] + rk[k];
            ebuf[pos] = ((unsigned long long)(unsigned)dst[k] << 32) | (unsigned)src[k];
        }
    }
}

__global__ __launch_bounds__(256) void csr_it_kernel(
    int n, const unsigned long long* __restrict__ ebuf, const int* __restrict__ bbase,
    int* __restrict__ row_it, int* __restrict__ deg_it,
    float* __restrict__ inv_cnt, int* __restrict__ col_it)
{
    __shared__ int ldeg[1024];
    __shared__ int lnext[1024];
    __shared__ int lpart[256];
    const int b = blockIdx.x;
    const int t = threadIdx.x;
    const int node_lo = b << 10;
    const int nn = min(1024, n - node_lo);
    const int e0 = bbase[b], e1 = bbase[b + 1];

    for (int i = t; i < nn; i += 256) ldeg[i] = 0;
    __syncthreads();
    for (int i = e0 + t; i < e1; i += 256)
        atomicAdd(&ldeg[(int)(ebuf[i] >> 32) - node_lo], 1);
    __syncthreads();

    const int i4 = 4 * t;
    int l0 = (i4     < nn) ? ldeg[i4]     : 0;
    int l1 = (i4 + 1 < nn) ? ldeg[i4 + 1] : 0;
    int l2 = (i4 + 2 < nn) ? ldeg[i4 + 2] : 0;
    int l3 = (i4 + 3 < nn) ? ldeg[i4 + 3] : 0;
    const int lsum = l0 + l1 + l2 + l3;
    lpart[t] = lsum;
    __syncthreads();
    for (int off = 1; off < 256; off <<= 1) {
        int v = (t >= off) ? lpart[t - off] : 0;
        __syncthreads();
        if (t >= off) lpart[t] += v;
        __syncthreads();
    }
    const int ex = lpart[t] - lsum;

    const int p[4] = {ex, ex + l0, ex + l0 + l1, ex + l0 + l1 + l2};
    const int l[4] = {l0, l1, l2, l3};
#pragma unroll
    for (int k = 0; k < 4; k++) {
        int i = i4 + k;
        if (i < nn) {
            lnext[i] = p[k];
            row_it[node_lo + i]  = e0 + p[k];
            deg_it[node_lo + i]  = l[k];
            inv_cnt[node_lo + i] = 1.0f / (float)max(l[k], 1);
        }
    }
    __syncthreads();
    for (int i = e0 + t; i < e1; i += 256) {
        unsigned long long v = ebuf[i];
        int dstl = (int)(v >> 32) - node_lo;
        int pos  = atomicAdd(&lnext[dstl], 1);
        col_it[e0 + pos] = (int)(v & 0xffffffffu);
    }
}

// ---------------- Aggregation (C=32): 8 nodes per wave ----------------
// Each 8-lane group owns one node (lane&7 = channel quad). No shuffles;
// unroll-4 keeps up to 32 row-gathers in flight per wave. 32 nodes/block.

__global__ __launch_bounds__(256, 8) void agg32_kernel(
    int n, const float* __restrict__ hin,
    const int* __restrict__ row_it, const int* __restrict__ deg_it, const int* __restrict__ col_it,
    const int* __restrict__ row_tp, const int* __restrict__ deg_tp, const int* __restrict__ col_tp,
    const float* __restrict__ inv_cnt, float* __restrict__ agg)
{
    const int wave = threadIdx.x >> 6;
    const int lane = threadIdx.x & 63;
    const int g = lane >> 3;           // node slot within wave
    const int q = lane & 7;            // channel quad: c = 4q..4q+3
    const int node = (blockIdx.x * 4 + wave) * 8 + g;
    if (node >= n) return;

    float4 aA = make_float4(0.f, 0.f, 0.f, 0.f);
    float4 aM = make_float4(0.f, 0.f, 0.f, 0.f);

    {   // temp_previous, aggr = add (avg degree ~1)
        const int rs = row_tp[node], d = deg_tp[node];
        for (int e = 0; e < d; e++) {
            const int j = col_tp[rs + e];
            const float4 v = *(const float4*)&hin[(size_t)j * 32 + q * 4];
            aA.x += v.x; aA.y += v.y; aA.z += v.z; aA.w += v.w;
        }
    }
    {   // intersects, aggr = mean (avg degree ~16), unroll 4 for MLP
        const int rs = row_it[node], d = deg_it[node];
        int e = 0;
        for (; e + 3 < d; e += 4) {
            const int j0 = col_it[rs + e];
            const int j1 = col_it[rs + e + 1];
            const int j2 = col_it[rs + e + 2];
            const int j3 = col_it[rs + e + 3];
            const float4 v0 = *(const float4*)&hin[(size_t)j0 * 32 + q * 4];
            const float4 v1 = *(const float4*)&hin[(size_t)j1 * 32 + q * 4];
            const float4 v2 = *(const float4*)&hin[(size_t)j2 * 32 + q * 4];
            const float4 v3 = *(const float4*)&hin[(size_t)j3 * 32 + q * 4];
            aM.x += (v0.x + v1.x) + (v2.x + v3.x);
            aM.y += (v0.y + v1.y) + (v2.y + v3.y);
            aM.z += (v0.z + v1.z) + (v2.z + v3.z);
            aM.w += (v0.w + v1.w) + (v2.w + v3.w);
        }
        for (; e < d; e++) {
            const int j = col_it[rs + e];
            const float4 v = *(const float4*)&hin[(size_t)j * 32 + q * 4];
            aM.x += v.x; aM.y += v.y; aM.z += v.z; aM.w += v.w;
        }
    }

    const float ic = inv_cnt[node];
    aM.x *= ic; aM.y *= ic; aM.z *= ic; aM.w *= ic;
    *(float4*)&agg[(size_t)node * 64 + q * 4]      = aA;
    *(float4*)&agg[(size_t)node * 64 + 32 + q * 4] = aM;
}

// ---------------- Aggregation (C=6, head): 8 nodes per wave ----------------

__global__ __launch_bounds__(256, 8) void agg6_kernel(
    int n, const float* __restrict__ hin,
    const int* __restrict__ row_it, const int* __restrict__ deg_it, const int* __restrict__ col_it,
    const int* __restrict__ row_tp, const int* __restrict__ deg_tp, const int* __restrict__ col_tp,
    const float* __restrict__ inv_cnt, float* __restrict__ agg)
{
    const int wave = threadIdx.x >> 6;
    const int lane = threadIdx.x & 63;
    const int g = lane >> 3;
    const int c = lane & 7;
    const int cc = (c < 6) ? c : 0;    // lanes c>=6 load in-bounds, never write
    const int node = (blockIdx.x * 4 + wave) * 8 + g;
    if (node >= n) return;

    float aA = 0.f, aM = 0.f;
    {
        const int rs = row_tp[node], d = deg_tp[node];
        for (int e = 0; e < d; e++) {
            const int j = col_tp[rs + e];
            aA += hin[(size_t)j * 6 + cc];
        }
    }
    {
        const int rs = row_it[node], d = deg_it[node];
        int e = 0;
        for (; e + 3 < d; e += 4) {
            const int j0 = col_it[rs + e];
            const int j1 = col_it[rs + e + 1];
            const int j2 = col_it[rs + e + 2];
            const int j3 = col_it[rs + e + 3];
            aM += (hin[(size_t)j0 * 6 + cc] + hin[(size_t)j1 * 6 + cc])
                + (hin[(size_t)j2 * 6 + cc] + hin[(size_t)j3 * 6 + cc]);
        }
        for (; e < d; e++) {
            const int j = col_it[rs + e];
            aM += hin[(size_t)j * 6 + cc];
        }
    }

    if (c < 6) {
        agg[(size_t)node * 12 + c]     = aA;
        agg[(size_t)node * 12 + 6 + c] = aM * inv_cnt[node];
    }
}

// ---------------- Per-layer GEMM ----------------

template <int CI, bool RESID>
__global__ __launch_bounds__(128) void gemm_kernel(
    int n, const float* __restrict__ agg, const float* __restrict__ hin,
    const float* __restrict__ Wrel0, const float* __restrict__ Wrel1,
    const float* __restrict__ Wroot0, const float* __restrict__ Wroot1,
    const float* __restrict__ bias0, const float* __restrict__ bias1,
    float* __restrict__ hout)
{
    constexpr int K  = 3 * CI;
    constexpr int KC = (CI == 6) ? 18 : 16;
    constexpr int NCHUNK = K / KC;
    constexpr int LDA = 260;

    __shared__ float sW[K * 32];
    __shared__ float sB[32];
    __shared__ float sA[KC * LDA];

    const int tid = threadIdx.x;
    for (int idx = tid; idx < K * 32; idx += 128) {
        int k = idx >> 5, co = idx & 31;
        float w;
        if (k < CI)            w = Wrel0[k * 32 + co];
        else if (k < 2 * CI)   w = Wrel1[(k - CI) * 32 + co];
        else                   w = Wroot0[(k - 2 * CI) * 32 + co] + Wroot1[(k - 2 * CI) * 32 + co];
        sW[idx] = w;
    }
    if (tid < 32) sB[tid] = bias0[tid] + bias1[tid];

    const int n0 = blockIdx.x * 256;
    const int cg = tid & 3;
    const int ng = tid >> 2;

    float acc[8][8];
#pragma unroll
    for (int i = 0; i < 8; i++)
#pragma unroll
        for (int j = 0; j < 8; j++) acc[i][j] = 0.f;

    for (int ch = 0; ch < NCHUNK; ch++) {
        const int k0 = ch * KC;
        __syncthreads();
        for (int idx = tid; idx < KC * 256; idx += 128) {
            int kk, nn;
            if constexpr ((KC & (KC - 1)) == 0) { kk = idx & (KC - 1); nn = idx >> 4; }
            else                                { kk = idx % KC;       nn = idx / KC; }
            int node = n0 + nn;
            int k = k0 + kk;
            float v = 0.f;
            if (node < n) {
                v = (k < 2 * CI) ? agg[(size_t)node * (2 * CI) + k]
                                 : hin[(size_t)node * CI + (k - 2 * CI)];
            }
            sA[kk * LDA + nn] = v;
        }
        __syncthreads();
#pragma unroll
        for (int kk = 0; kk < KC; kk++) {
            const float4 a0 = *(const float4*)&sA[kk * LDA + ng * 8];
            const float4 a1 = *(const float4*)&sA[kk * LDA + ng * 8 + 4];
            const int k = k0 + kk;
            const float4 w0 = *(const float4*)&sW[k * 32 + cg * 8];
            const float4 w1 = *(const float4*)&sW[k * 32 + cg * 8 + 4];
            const float av[8] = {a0.x, a0.y, a0.z, a0.w, a1.x, a1.y, a1.z, a1.w};
            const float wv[8] = {w0.x, w0.y, w0.z, w0.w, w1.x, w1.y, w1.z, w1.w};
#pragma unroll
            for (int i = 0; i < 8; i++)
#pragma unroll
                for (int j = 0; j < 8; j++) acc[i][j] += av[i] * wv[j];
        }
    }

    const int cbase = cg * 8;
#pragma unroll
    for (int i = 0; i < 8; i++) {
        int node = n0 + ng * 8 + i;
        if (node < n) {
            float r[8];
#pragma unroll
            for (int j = 0; j < 8; j++) r[j] = acc[i][j] + sB[cbase + j];
            if (RESID) {
                const float4 h0 = *(const float4*)&hin[(size_t)node * 32 + cbase];
                const float4 h1 = *(const float4*)&hin[(size_t)node * 32 + cbase + 4];
                r[0] += h0.x; r[1] += h0.y; r[2] += h0.z; r[3] += h0.w;
                r[4] += h1.x; r[5] += h1.y; r[6] += h1.z; r[7] += h1.w;
            }
#pragma unroll
            for (int j = 0; j < 8; j++) r[j] = fmaxf(r[j], 0.f);
            *(float4*)&hout[(size_t)node * 32 + cbase]     = make_float4(r[0], r[1], r[2], r[3]);
            *(float4*)&hout[(size_t)node * 32 + cbase + 4] = make_float4(r[4], r[5], r[6], r[7]);
        }
    }
}

// ---------------- Final linear: out = h @ Wout + bout ----------------
// v3: 64-node x 128-col tile, per-thread 4x8. NO min-waves clause — R4's
// __launch_bounds__(256,4) forced VGPR=64 and spilled acc to scratch
// (FETCH 1.8 GB). Plain bounds + unroll 8 keeps VGPR ~128, no spill.

__global__ __launch_bounds__(256) void final_kernel(
    int n, const float* __restrict__ h, const float* __restrict__ Wout,
    const float* __restrict__ bout, float* __restrict__ out)
{
    constexpr int LDH = 68;   // 64+4: 16B-aligned rows, breaks pow2 stride
    __shared__ float sW[32 * 128];
    __shared__ float sB[128];
    __shared__ float sHT[32 * LDH];

    const int tid = threadIdx.x;
    for (int idx = tid; idx < 4096; idx += 256) sW[idx] = Wout[idx];
    if (tid < 128) sB[tid] = bout[tid];

    const int n0 = blockIdx.x * 64;
    for (int idx = tid; idx < 2048; idx += 256) {
        int k = idx & 31, nn = idx >> 5;
        int node = n0 + nn;
        sHT[k * LDH + nn] = (node < n) ? h[(size_t)node * 32 + k] : 0.f;
    }
    __syncthreads();

    const int cg = tid & 15;   // 16 col groups x 8 cols
    const int ng = tid >> 4;   // 16 node groups x 4 nodes
    float acc[4][8];
#pragma unroll
    for (int i = 0; i < 4; i++)
#pragma unroll
        for (int j = 0; j < 8; j++) acc[i][j] = 0.f;

#pragma unroll 8
    for (int k = 0; k < 32; k++) {
        const float4 a  = *(const float4*)&sHT[k * LDH + ng * 4];
        const float4 w0 = *(const float4*)&sW[k * 128 + cg * 8];
        const float4 w1 = *(const float4*)&sW[k * 128 + cg * 8 + 4];
        const float av[4] = {a.x, a.y, a.z, a.w};
        const float wv[8] = {w0.x, w0.y, w0.z, w0.w, w1.x, w1.y, w1.z, w1.w};
#pragma unroll
        for (int i = 0; i < 4; i++)
#pragma unroll
            for (int j = 0; j < 8; j++) acc[i][j] += av[i] * wv[j];
    }

    const int cbase = cg * 8;
#pragma unroll
    for (int i = 0; i < 4; i++) {
        int node = n0 + ng * 4 + i;
        if (node < n) {
            float r[8];
#pragma unroll
            for (int j = 0; j < 8; j++) r[j] = acc[i][j] + sB[cbase + j];
            *(float4*)&out[(size_t)node * 128 + cbase]     = make_float4(r[0], r[1], r[2], r[3]);
            *(float4*)&out[(size_t)node * 128 + cbase + 4] = make_float4(r[4], r[5], r[6], r[7]);
        }
    }
}

// ---------------- launch ----------------

extern "C" void kernel_launch(void* const* d_in, const int* in_sizes, int n_in,
                              void* d_out, int out_size, void* d_ws, size_t ws_size,
                              hipStream_t stream)
{
    const float* x      = (const float*)d_in[0];
    const int*   ei_tp  = (const int*)d_in[1];
    const int*   ei_it  = (const int*)d_in[2];
    const float* W0_rel  = (const float*)d_in[3];
    const float* W0_root = (const float*)d_in[4];
    const float* b0      = (const float*)d_in[5];
    const float* W_rel   = (const float*)d_in[6];
    const float* W_root  = (const float*)d_in[7];
    const float* b       = (const float*)d_in[8];
    const float* Wout    = (const float*)d_in[9];
    const float* bout    = (const float*)d_in[10];
    float* out = (float*)d_out;

    const int n    = in_sizes[0] / 6;
    const int E_tp = in_sizes[1] / 2;
    const int E_it = in_sizes[2] / 2;
    const int B    = (n + 1023) >> 10;

    float* h0      = (float*)d_ws;
    float* h1      = h0 + (size_t)n * 32;
    int*   deg_it  = (int*)(h1 + (size_t)n * 32);
    int*   row_it  = deg_it + n;
    float* inv_cnt = (float*)(row_it + n);
    int*   deg_tp  = (int*)(inv_cnt + n);
    int*   ctr     = deg_tp + n;
    int*   bcnt    = ctr + 1;
    int*   bbase   = bcnt + 256;
    int*   bcursor = bbase + 257;
    int*   row_tp  = bcursor + 256;
    int*   next_tp = row_tp + n;
    int*   col_it  = next_tp + n;
    int*   col_tp  = col_it + E_it;
    unsigned long long* ebuf = (unsigned long long*)d_out;
    float* aggbuf = (float*)d_out;

    hipMemsetAsync(deg_tp, 0, (size_t)(n + 1 + 256) * sizeof(int), stream);

    bucket_count_kernel<<<512, 256, 0, stream>>>(ei_it, E_it, B, bcnt);
    bucket_prefix_kernel<<<1, 256, 0, stream>>>(B, bcnt, bbase, bcursor);
    multisplit_kernel<<<(E_it + 2047) / 2048, 256, 0, stream>>>(ei_it, E_it, bcursor, ebuf);
    csr_it_kernel<<<B, 256, 0, stream>>>(n, ebuf, bbase, row_it, deg_it, inv_cnt, col_it);

    hist_tp_kernel<<<(E_tp + 255) / 256, 256, 0, stream>>>(ei_tp, E_tp, deg_tp);
    alloc_tp_kernel<<<(n + 255) / 256, 256, 0, stream>>>(n, deg_tp, row_tp, next_tp, ctr);
    fill_tp_kernel<<<(E_tp + 255) / 256, 256, 0, stream>>>(ei_tp, E_tp, next_tp, col_tp);

    const int agg_blocks  = (n + 31) / 32;   // 32 nodes/block (8 per wave)
    const int gemm_blocks = (n + 255) / 256;

    agg6_kernel<<<agg_blocks, 256, 0, stream>>>(n, x, row_it, deg_it, col_it,
                                                row_tp, deg_tp, col_tp, inv_cnt, aggbuf);
    gemm_kernel<6, false><<<gemm_blocks, 128, 0, stream>>>(
        n, aggbuf, x,
        W0_rel, W0_rel + 192, W0_root, W0_root + 192, b0, b0 + 32, h0);

    float* hin  = h0;
    float* hout = h1;
    for (int l = 0; l < 4; l++) {
        agg32_kernel<<<agg_blocks, 256, 0, stream>>>(n, hin, row_it, deg_it, col_it,
                                                     row_tp, deg_tp, col_tp, inv_cnt, aggbuf);
        gemm_kernel<32, true><<<gemm_blocks, 128, 0, stream>>>(
            n, aggbuf, hin,
            W_rel + (size_t)l * 2048, W_rel + (size_t)l * 2048 + 1024,
            W_root + (size_t)l * 2048, W_root + (size_t)l * 2048 + 1024,
            b + (size_t)l * 64, b + (size_t)l * 64 + 32, hout);
        float* t = hin; hin = hout; hout = t;
    }

    final_kernel<<<(n + 63) / 64, 256, 0, stream>>>(n, hin, Wout, bout, out);
}

// Round 6
// 979.338 us; speedup vs baseline: 2.3858x; 1.2812x over previous
//
#include <hip/hip_runtime.h>

// n must be <= 256*1024 for the bucket scheme (bucket = dst >> 10, B <= 256).

// ---------------- CSR build: tp (small, 200K edges) — old path ----------------

__global__ __launch_bounds__(256) void hist_tp_kernel(
    const int* __restrict__ ei_tp, int E_tp, int* __restrict__ deg_tp)
{
    int i = blockIdx.x * 256 + threadIdx.x;
    if (i < E_tp) atomicAdd(&deg_tp[ei_tp[E_tp + i]], 1);
}

__global__ __launch_bounds__(256) void alloc_tp_kernel(
    int n, const int* __restrict__ deg_tp,
    int* __restrict__ row_tp, int* __restrict__ next_tp, int* __restrict__ ctr)
{
    int i = blockIdx.x * 256 + threadIdx.x;
    if (i >= n) return;
    int d = deg_tp[i];
    int r = atomicAdd(&ctr[0], d);
    row_tp[i] = r; next_tp[i] = r;
}

__global__ __launch_bounds__(256) void fill_tp_kernel(
    const int* __restrict__ ei_tp, int E_tp,
    int* __restrict__ next_tp, int* __restrict__ col_tp)
{
    int i = blockIdx.x * 256 + threadIdx.x;
    if (i >= E_tp) return;
    int src = ei_tp[i];
    int dst = ei_tp[E_tp + i];
    col_tp[atomicAdd(&next_tp[dst], 1)] = src;
}

// ---------------- CSR build: it (3.2M edges) — two-level multisplit ----------------

__global__ __launch_bounds__(256) void bucket_count_kernel(
    const int* __restrict__ ei_it, int E_it, int B, int* __restrict__ bcnt)
{
    __shared__ int h[256];
    h[threadIdx.x] = 0;
    __syncthreads();
    const int stride = gridDim.x * 256;
    for (int i = blockIdx.x * 256 + threadIdx.x; i < E_it; i += stride)
        atomicAdd(&h[ei_it[E_it + i] >> 10], 1);
    __syncthreads();
    int v = h[threadIdx.x];
    if (threadIdx.x < B && v) atomicAdd(&bcnt[threadIdx.x], v);
}

__global__ __launch_bounds__(256) void bucket_prefix_kernel(
    int B, const int* __restrict__ bcnt, int* __restrict__ bbase, int* __restrict__ bcursor)
{
    __shared__ int s[256];
    const int t = threadIdx.x;
    s[t] = (t < B) ? bcnt[t] : 0;
    __syncthreads();
    for (int off = 1; off < 256; off <<= 1) {
        int v = (t >= off) ? s[t - off] : 0;
        __syncthreads();
        if (t >= off) s[t] += v;
        __syncthreads();
    }
    if (t == 0) bbase[0] = 0;
    if (t < B) {
        bbase[t + 1] = s[t];
        bcursor[t] = s[t] - bcnt[t];
    }
}

__global__ __launch_bounds__(256) void multisplit_kernel(
    const int* __restrict__ ei_it, int E_it,
    int* __restrict__ bcursor, unsigned long long* __restrict__ ebuf)
{
    __shared__ int cnt[256];
    __shared__ int gbase[256];
    const int tid  = threadIdx.x;
    const int base = blockIdx.x * 2048;
    cnt[tid] = 0;
    __syncthreads();

    int src[8], dst[8], rk[8], bk[8];
#pragma unroll
    for (int k = 0; k < 8; k++) {
        int i = base + k * 256 + tid;
        if (i < E_it) {
            src[k] = ei_it[i];
            dst[k] = ei_it[E_it + i];
            bk[k]  = dst[k] >> 10;
            rk[k]  = atomicAdd(&cnt[bk[k]], 1);
        } else rk[k] = -1;
    }
    __syncthreads();
    int c = cnt[tid];
    if (c) gbase[tid] = atomicAdd(&bcursor[tid], c);
    __syncthreads();
#pragma unroll
    for (int k = 0; k < 8; k++) {
        if (rk[k] >= 0) {
            int pos = gbase[bk[k]] + rk[k];
            ebuf[pos] = ((unsigned long long)(unsigned)dst[k] << 32) | (unsigned)src[k];
        }
    }
}

__global__ __launch_bounds__(256) void csr_it_kernel(
    int n, const unsigned long long* __restrict__ ebuf, const int* __restrict__ bbase,
    int* __restrict__ row_it, int* __restrict__ deg_it,
    float* __restrict__ inv_cnt, int* __restrict__ col_it)
{
    __shared__ int ldeg[1024];
    __shared__ int lnext[1024];
    __shared__ int lpart[256];
    const int b = blockIdx.x;
    const int t = threadIdx.x;
    const int node_lo = b << 10;
    const int nn = min(1024, n - node_lo);
    const int e0 = bbase[b], e1 = bbase[b + 1];

    for (int i = t; i < nn; i += 256) ldeg[i] = 0;
    __syncthreads();
    for (int i = e0 + t; i < e1; i += 256)
        atomicAdd(&ldeg[(int)(ebuf[i] >> 32) - node_lo], 1);
    __syncthreads();

    const int i4 = 4 * t;
    int l0 = (i4     < nn) ? ldeg[i4]     : 0;
    int l1 = (i4 + 1 < nn) ? ldeg[i4 + 1] : 0;
    int l2 = (i4 + 2 < nn) ? ldeg[i4 + 2] : 0;
    int l3 = (i4 + 3 < nn) ? ldeg[i4 + 3] : 0;
    const int lsum = l0 + l1 + l2 + l3;
    lpart[t] = lsum;
    __syncthreads();
    for (int off = 1; off < 256; off <<= 1) {
        int v = (t >= off) ? lpart[t - off] : 0;
        __syncthreads();
        if (t >= off) lpart[t] += v;
        __syncthreads();
    }
    const int ex = lpart[t] - lsum;

    const int p[4] = {ex, ex + l0, ex + l0 + l1, ex + l0 + l1 + l2};
    const int l[4] = {l0, l1, l2, l3};
#pragma unroll
    for (int k = 0; k < 4; k++) {
        int i = i4 + k;
        if (i < nn) {
            lnext[i] = p[k];
            row_it[node_lo + i]  = e0 + p[k];
            deg_it[node_lo + i]  = l[k];
            inv_cnt[node_lo + i] = 1.0f / (float)max(l[k], 1);
        }
    }
    __syncthreads();
    for (int i = e0 + t; i < e1; i += 256) {
        unsigned long long v = ebuf[i];
        int dstl = (int)(v >> 32) - node_lo;
        int pos  = atomicAdd(&lnext[dstl], 1);
        col_it[e0 + pos] = (int)(v & 0xffffffffu);
    }
}

// ---------------- Weight prep: Wcat = [Wrel0 | Wrel1 | Wroot0+Wroot1], bias sums ----
// Layout (floats): head W 18x32 @ 0; layer l W 96x32 @ 576 + l*3072;
// head bias 32 @ 12864; layer l bias 32 @ 12896 + l*32. Total 13024.

__global__ __launch_bounds__(256) void prep_weights_kernel(
    const float* __restrict__ W0_rel, const float* __restrict__ W0_root,
    const float* __restrict__ b0, const float* __restrict__ W_rel,
    const float* __restrict__ W_root, const float* __restrict__ b,
    float* __restrict__ wcat)
{
    int i = blockIdx.x * 256 + threadIdx.x;
    if (i < 576) {
        int k = i >> 5, j = i & 31;
        float v;
        if (k < 6)       v = W0_rel[k * 32 + j];
        else if (k < 12) v = W0_rel[192 + (k - 6) * 32 + j];
        else             v = W0_root[(k - 12) * 32 + j] + W0_root[192 + (k - 12) * 32 + j];
        wcat[i] = v;
    } else if (i < 576 + 4 * 3072) {
        int t = i - 576;
        int l = t / 3072, r = t % 3072;
        int k = r >> 5, j = r & 31;
        const float* Wr = W_rel  + l * 2048;
        const float* Wt = W_root + l * 2048;
        float v;
        if (k < 32)      v = Wr[k * 32 + j];
        else if (k < 64) v = Wr[1024 + (k - 32) * 32 + j];
        else             v = Wt[(k - 64) * 32 + j] + Wt[1024 + (k - 64) * 32 + j];
        wcat[i] = v;
    } else if (i < 13024) {
        int t = i - 12864;
        if (t < 32) wcat[i] = b0[t] + b0[32 + t];
        else {
            int l = (t - 32) >> 5, j = (t - 32) & 31;
            wcat[i] = b[l * 64 + j] + b[l * 64 + 32 + j];
        }
    }
}

// ---------------- Aggregation (C=32): 8 nodes per wave ----------------

__global__ __launch_bounds__(256, 8) void agg32_kernel(
    int n, const float* __restrict__ hin,
    const int* __restrict__ row_it, const int* __restrict__ deg_it, const int* __restrict__ col_it,
    const int* __restrict__ row_tp, const int* __restrict__ deg_tp, const int* __restrict__ col_tp,
    const float* __restrict__ inv_cnt, float* __restrict__ agg)
{
    const int wave = threadIdx.x >> 6;
    const int lane = threadIdx.x & 63;
    const int g = lane >> 3;
    const int q = lane & 7;
    const int node = (blockIdx.x * 4 + wave) * 8 + g;
    if (node >= n) return;

    float4 aA = make_float4(0.f, 0.f, 0.f, 0.f);
    float4 aM = make_float4(0.f, 0.f, 0.f, 0.f);

    {
        const int rs = row_tp[node], d = deg_tp[node];
        for (int e = 0; e < d; e++) {
            const int j = col_tp[rs + e];
            const float4 v = *(const float4*)&hin[(size_t)j * 32 + q * 4];
            aA.x += v.x; aA.y += v.y; aA.z += v.z; aA.w += v.w;
        }
    }
    {
        const int rs = row_it[node], d = deg_it[node];
        int e = 0;
        for (; e + 3 < d; e += 4) {
            const int j0 = col_it[rs + e];
            const int j1 = col_it[rs + e + 1];
            const int j2 = col_it[rs + e + 2];
            const int j3 = col_it[rs + e + 3];
            const float4 v0 = *(const float4*)&hin[(size_t)j0 * 32 + q * 4];
            const float4 v1 = *(const float4*)&hin[(size_t)j1 * 32 + q * 4];
            const float4 v2 = *(const float4*)&hin[(size_t)j2 * 32 + q * 4];
            const float4 v3 = *(const float4*)&hin[(size_t)j3 * 32 + q * 4];
            aM.x += (v0.x + v1.x) + (v2.x + v3.x);
            aM.y += (v0.y + v1.y) + (v2.y + v3.y);
            aM.z += (v0.z + v1.z) + (v2.z + v3.z);
            aM.w += (v0.w + v1.w) + (v2.w + v3.w);
        }
        for (; e < d; e++) {
            const int j = col_it[rs + e];
            const float4 v = *(const float4*)&hin[(size_t)j * 32 + q * 4];
            aM.x += v.x; aM.y += v.y; aM.z += v.z; aM.w += v.w;
        }
    }

    const float ic = inv_cnt[node];
    aM.x *= ic; aM.y *= ic; aM.z *= ic; aM.w *= ic;
    *(float4*)&agg[(size_t)node * 64 + q * 4]      = aA;
    *(float4*)&agg[(size_t)node * 64 + 32 + q * 4] = aM;
}

// ---------------- Aggregation (C=6, head): 8 nodes per wave ----------------

__global__ __launch_bounds__(256, 8) void agg6_kernel(
    int n, const float* __restrict__ hin,
    const int* __restrict__ row_it, const int* __restrict__ deg_it, const int* __restrict__ col_it,
    const int* __restrict__ row_tp, const int* __restrict__ deg_tp, const int* __restrict__ col_tp,
    const float* __restrict__ inv_cnt, float* __restrict__ agg)
{
    const int wave = threadIdx.x >> 6;
    const int lane = threadIdx.x & 63;
    const int g = lane >> 3;
    const int c = lane & 7;
    const int cc = (c < 6) ? c : 0;
    const int node = (blockIdx.x * 4 + wave) * 8 + g;
    if (node >= n) return;

    float aA = 0.f, aM = 0.f;
    {
        const int rs = row_tp[node], d = deg_tp[node];
        for (int e = 0; e < d; e++) {
            const int j = col_tp[rs + e];
            aA += hin[(size_t)j * 6 + cc];
        }
    }
    {
        const int rs = row_it[node], d = deg_it[node];
        int e = 0;
        for (; e + 3 < d; e += 4) {
            const int j0 = col_it[rs + e];
            const int j1 = col_it[rs + e + 1];
            const int j2 = col_it[rs + e + 2];
            const int j3 = col_it[rs + e + 3];
            aM += (hin[(size_t)j0 * 6 + cc] + hin[(size_t)j1 * 6 + cc])
                + (hin[(size_t)j2 * 6 + cc] + hin[(size_t)j3 * 6 + cc]);
        }
        for (; e < d; e++) {
            const int j = col_it[rs + e];
            aM += hin[(size_t)j * 6 + cc];
        }
    }

    if (c < 6) {
        agg[(size_t)node * 12 + c]     = aA;
        agg[(size_t)node * 12 + 6 + c] = aM * inv_cnt[node];
    }
}

// ---------------- Per-layer GEMM, register version ----------------
// One thread = one node; acc[32] in VGPRs; A-row via float4 global loads;
// W/bias at thread-uniform indices (scalar loads). No LDS, no barriers.

template <int CI, bool RESID>
__global__ __launch_bounds__(256) void gemm_reg_kernel(
    int n, const float* __restrict__ agg, const float* __restrict__ hin,
    const float* __restrict__ Wcat, const float* __restrict__ bias,
    float* __restrict__ hout)
{
    const int node = blockIdx.x * 256 + threadIdx.x;
    if (node >= n) return;

    float acc[32];
#pragma unroll
    for (int j = 0; j < 32; j++) acc[j] = bias[j];

    if constexpr (CI == 32) {
        const float* arow = agg + (size_t)node * 64;
#pragma unroll
        for (int c = 0; c < 8; c++) {
            const float4 a0 = *(const float4*)(arow + c * 8);
            const float4 a1 = *(const float4*)(arow + c * 8 + 4);
            const float av[8] = {a0.x, a0.y, a0.z, a0.w, a1.x, a1.y, a1.z, a1.w};
#pragma unroll
            for (int kk = 0; kk < 8; kk++) {
                const float* wr = Wcat + (c * 8 + kk) * 32;
#pragma unroll
                for (int j = 0; j < 32; j++) acc[j] = fmaf(av[kk], wr[j], acc[j]);
            }
        }
        const float* hrow = hin + (size_t)node * 32;
#pragma unroll
        for (int c = 0; c < 4; c++) {
            const float4 a0 = *(const float4*)(hrow + c * 8);
            const float4 a1 = *(const float4*)(hrow + c * 8 + 4);
            const float av[8] = {a0.x, a0.y, a0.z, a0.w, a1.x, a1.y, a1.z, a1.w};
#pragma unroll
            for (int kk = 0; kk < 8; kk++) {
                const float* wr = Wcat + (64 + c * 8 + kk) * 32;
#pragma unroll
                for (int j = 0; j < 32; j++) acc[j] = fmaf(av[kk], wr[j], acc[j]);
            }
            if (RESID) {
#pragma unroll
                for (int kk = 0; kk < 8; kk++) acc[c * 8 + kk] += av[kk];
            }
        }
    } else {  // CI == 6, K = 18
        const float* arow = agg + (size_t)node * 12;
#pragma unroll
        for (int k = 0; k < 12; k++) {
            const float a = arow[k];
            const float* wr = Wcat + k * 32;
#pragma unroll
            for (int j = 0; j < 32; j++) acc[j] = fmaf(a, wr[j], acc[j]);
        }
        const float* xrow = hin + (size_t)node * 6;
#pragma unroll
        for (int k = 0; k < 6; k++) {
            const float a = xrow[k];
            const float* wr = Wcat + (12 + k) * 32;
#pragma unroll
            for (int j = 0; j < 32; j++) acc[j] = fmaf(a, wr[j], acc[j]);
        }
    }

#pragma unroll
    for (int j = 0; j < 32; j++) acc[j] = fmaxf(acc[j], 0.f);
    float* orow = hout + (size_t)node * 32;
#pragma unroll
    for (int j = 0; j < 32; j += 4)
        *(float4*)(orow + j) = make_float4(acc[j], acc[j + 1], acc[j + 2], acc[j + 3]);
}

// ---------------- Final linear, register version ----------------
// Wave = column group (wave-uniform W indices -> scalar loads);
// lane = node. 64 nodes x 128 cols per 256-thread block.

__global__ __launch_bounds__(256) void final_kernel(
    int n, const float* __restrict__ h, const float* __restrict__ Wout,
    const float* __restrict__ bout, float* __restrict__ out)
{
    const int wave = threadIdx.x >> 6;
    const int lane = threadIdx.x & 63;
    const int node = blockIdx.x * 64 + lane;
    const int cbase = wave * 32;
    if (node >= n) return;

    float acc[32];
#pragma unroll
    for (int j = 0; j < 32; j++) acc[j] = bout[cbase + j];

    const float* hrow = h + (size_t)node * 32;
#pragma unroll
    for (int c = 0; c < 4; c++) {
        const float4 a0 = *(const float4*)(hrow + c * 8);
        const float4 a1 = *(const float4*)(hrow + c * 8 + 4);
        const float av[8] = {a0.x, a0.y, a0.z, a0.w, a1.x, a1.y, a1.z, a1.w};
#pragma unroll
        for (int kk = 0; kk < 8; kk++) {
            const float* wr = Wout + (c * 8 + kk) * 128 + cbase;
#pragma unroll
            for (int j = 0; j < 32; j++) acc[j] = fmaf(av[kk], wr[j], acc[j]);
        }
    }

    float* orow = out + (size_t)node * 128 + cbase;
#pragma unroll
    for (int j = 0; j < 32; j += 4)
        *(float4*)(orow + j) = make_float4(acc[j], acc[j + 1], acc[j + 2], acc[j + 3]);
}

// ---------------- launch ----------------

extern "C" void kernel_launch(void* const* d_in, const int* in_sizes, int n_in,
                              void* d_out, int out_size, void* d_ws, size_t ws_size,
                              hipStream_t stream)
{
    const float* x      = (const float*)d_in[0];
    const int*   ei_tp  = (const int*)d_in[1];
    const int*   ei_it  = (const int*)d_in[2];
    const float* W0_rel  = (const float*)d_in[3];
    const float* W0_root = (const float*)d_in[4];
    const float* b0      = (const float*)d_in[5];
    const float* W_rel   = (const float*)d_in[6];
    const float* W_root  = (const float*)d_in[7];
    const float* b       = (const float*)d_in[8];
    const float* Wout    = (const float*)d_in[9];
    const float* bout    = (const float*)d_in[10];
    float* out = (float*)d_out;

    const int n    = in_sizes[0] / 6;
    const int E_tp = in_sizes[1] / 2;
    const int E_it = in_sizes[2] / 2;
    const int B    = (n + 1023) >> 10;

    float* h0      = (float*)d_ws;
    float* h1      = h0 + (size_t)n * 32;
    int*   deg_it  = (int*)(h1 + (size_t)n * 32);
    int*   row_it  = deg_it + n;
    float* inv_cnt = (float*)(row_it + n);
    int*   deg_tp  = (int*)(inv_cnt + n);
    int*   ctr     = deg_tp + n;
    int*   bcnt    = ctr + 1;
    int*   bbase   = bcnt + 256;
    int*   bcursor = bbase + 257;
    int*   row_tp  = bcursor + 256;
    int*   next_tp = row_tp + n;
    int*   col_it  = next_tp + n;
    int*   col_tp  = col_it + E_it;
    float* wcat    = (float*)(col_tp + E_tp);   // 13024 floats
    unsigned long long* ebuf = (unsigned long long*)d_out;
    float* aggbuf = (float*)d_out;

    hipMemsetAsync(deg_tp, 0, (size_t)(n + 1 + 256) * sizeof(int), stream);

    prep_weights_kernel<<<51, 256, 0, stream>>>(W0_rel, W0_root, b0, W_rel, W_root, b, wcat);

    bucket_count_kernel<<<512, 256, 0, stream>>>(ei_it, E_it, B, bcnt);
    bucket_prefix_kernel<<<1, 256, 0, stream>>>(B, bcnt, bbase, bcursor);
    multisplit_kernel<<<(E_it + 2047) / 2048, 256, 0, stream>>>(ei_it, E_it, bcursor, ebuf);
    csr_it_kernel<<<B, 256, 0, stream>>>(n, ebuf, bbase, row_it, deg_it, inv_cnt, col_it);

    hist_tp_kernel<<<(E_tp + 255) / 256, 256, 0, stream>>>(ei_tp, E_tp, deg_tp);
    alloc_tp_kernel<<<(n + 255) / 256, 256, 0, stream>>>(n, deg_tp, row_tp, next_tp, ctr);
    fill_tp_kernel<<<(E_tp + 255) / 256, 256, 0, stream>>>(ei_tp, E_tp, next_tp, col_tp);

    const int agg_blocks  = (n + 31) / 32;
    const int gemm_blocks = (n + 255) / 256;

    agg6_kernel<<<agg_blocks, 256, 0, stream>>>(n, x, row_it, deg_it, col_it,
                                                row_tp, deg_tp, col_tp, inv_cnt, aggbuf);
    gemm_reg_kernel<6, false><<<gemm_blocks, 256, 0, stream>>>(
        n, aggbuf, x, wcat, wcat + 12864, h0);

    float* hin  = h0;
    float* hout = h1;
    for (int l = 0; l < 4; l++) {
        agg32_kernel<<<agg_blocks, 256, 0, stream>>>(n, hin, row_it, deg_it, col_it,
                                                     row_tp, deg_tp, col_tp, inv_cnt, aggbuf);
        gemm_reg_kernel<32, true><<<gemm_blocks, 256, 0, stream>>>(
            n, aggbuf, hin, wcat + 576 + l * 3072, wcat + 12896 + l * 32, hout);
        float* t = hin; hin = hout; hout = t;
    }

    final_kernel<<<(n + 63) / 64, 256, 0, stream>>>(n, hin, Wout, bout, out);
}